// Round 6
// baseline (235.801 us; speedup 1.0000x reference)
//
#include <hip/hip_runtime.h>
#include <math.h>

#define EPS 1e-5f
#define ROWS 4096  // B*N

typedef __attribute__((ext_vector_type(8))) short short8;
typedef __attribute__((ext_vector_type(4))) float floatx4;

__device__ inline short f2bf(float f) {
    unsigned u = __builtin_bit_cast(unsigned, f);
    unsigned r = (u + 0x7fffu + ((u >> 16) & 1u)) >> 16;
    return (short)r;
}
__device__ inline float bf2f(short s) {
    return __builtin_bit_cast(float, (unsigned)(unsigned short)s << 16);
}

// ---------------------------------------------------------------------------
// Fused prep: blocks [0,3072): LN(q/k/v)->bf16 ; [3072,4352): weights->bf16
// (Wup gets g2-scaled + per-row Bn/Wg dots) ; [4352,4621): zero stats buffers.
// ---------------------------------------------------------------------------
__global__ __launch_bounds__(256) void prep(
    const float* __restrict__ q, const float* __restrict__ k,
    const float* __restrict__ v, const float* __restrict__ g,
    const float* __restrict__ bb, short* __restrict__ qkvout,
    const float* __restrict__ w0, const float* __restrict__ w1,
    const float* __restrict__ w2, const float* __restrict__ w3,
    short* __restrict__ o0, short* __restrict__ o1,
    short* __restrict__ o2, short* __restrict__ o3,
    const float* __restrict__ g2, const float* __restrict__ b2n,
    float* __restrict__ Bn, float* __restrict__ Wg,
    float* __restrict__ zero0) {
    int bx = blockIdx.x;
    int t = threadIdx.x;
    if (bx < 3072) {  // layernorm of q/k/v, 4 rows per block
        int tensor = bx >> 10;
        int xb = bx & 1023;
        const float* x = tensor == 0 ? q : (tensor == 1 ? k : v);
        int row = xb * 4 + (t >> 6);
        int col = (t & 63) * 8;
        const float* xr = x + (size_t)row * 512 + col;
        float4 v0 = *(const float4*)xr;
        float4 v1 = *(const float4*)(xr + 4);
        float s = v0.x + v0.y + v0.z + v0.w + v1.x + v1.y + v1.z + v1.w;
        float sq = v0.x * v0.x + v0.y * v0.y + v0.z * v0.z + v0.w * v0.w +
                   v1.x * v1.x + v1.y * v1.y + v1.z * v1.z + v1.w * v1.w;
#pragma unroll
        for (int off = 32; off; off >>= 1) {
            s += __shfl_xor(s, off);
            sq += __shfl_xor(sq, off);
        }
        float m = s * (1.f / 512.f);
        float rstd = rsqrtf(sq * (1.f / 512.f) - m * m + EPS);
        float4 g0 = *(const float4*)(g + col);
        float4 g1 = *(const float4*)(g + col + 4);
        float4 b0 = *(const float4*)(bb + col);
        float4 b1 = *(const float4*)(bb + col + 4);
        short8 o;
        o[0] = f2bf((v0.x - m) * rstd * g0.x + b0.x);
        o[1] = f2bf((v0.y - m) * rstd * g0.y + b0.y);
        o[2] = f2bf((v0.z - m) * rstd * g0.z + b0.z);
        o[3] = f2bf((v0.w - m) * rstd * g0.w + b0.w);
        o[4] = f2bf((v1.x - m) * rstd * g1.x + b1.x);
        o[5] = f2bf((v1.y - m) * rstd * g1.y + b1.y);
        o[6] = f2bf((v1.z - m) * rstd * g1.z + b1.z);
        o[7] = f2bf((v1.w - m) * rstd * g1.w + b1.w);
        *(short8*)(qkvout + (size_t)(tensor * 4096 + row) * 512 + col) = o;
        return;
    }
    if (bx < 4352) {  // weight conversion, 2048 elems per block
        int wb = bx - 3072;
        if (wb >= 256 && wb < 768) {
            // Wup: scale by g2, plus per-row dots Bn = b2n.Wrow, Wg = g2.Wrow
            int base = wb - 256;
            int idx = base * 2048 + t * 8;
            int n = idx >> 9, c = idx & 511;
            float4 v0 = *(const float4*)(w2 + idx);
            float4 v1 = *(const float4*)(w2 + idx + 4);
            float4 ga = *(const float4*)(g2 + c);
            float4 gb = *(const float4*)(g2 + c + 4);
            float4 ba = *(const float4*)(b2n + c);
            float4 bbv = *(const float4*)(b2n + c + 4);
            short8 o;
            o[0] = f2bf(ga.x * v0.x); o[1] = f2bf(ga.y * v0.y);
            o[2] = f2bf(ga.z * v0.z); o[3] = f2bf(ga.w * v0.w);
            o[4] = f2bf(gb.x * v1.x); o[5] = f2bf(gb.y * v1.y);
            o[6] = f2bf(gb.z * v1.z); o[7] = f2bf(gb.w * v1.w);
            *(short8*)(o2 + idx) = o;
            float bn = ba.x * v0.x + ba.y * v0.y + ba.z * v0.z + ba.w * v0.w +
                       bbv.x * v1.x + bbv.y * v1.y + bbv.z * v1.z + bbv.w * v1.w;
            float wg = ga.x * v0.x + ga.y * v0.y + ga.z * v0.z + ga.w * v0.w +
                       gb.x * v1.x + gb.y * v1.y + gb.z * v1.z + gb.w * v1.w;
#pragma unroll
            for (int off = 32; off; off >>= 1) {
                bn += __shfl_xor(bn, off);
                wg += __shfl_xor(wg, off);
            }
            if ((t & 63) == 0) {
                Bn[n] = bn;
                Wg[n] = wg;
            }
            return;
        }
        const float* src;
        short* dst;
        int base;
        if (wb < 128) { src = w0; dst = o0; base = wb; }
        else if (wb < 256) { src = w1; dst = o1; base = wb - 128; }
        else { src = w3; dst = o3; base = wb - 768; }
        int idx = base * 2048 + t * 8;
        float4 v0 = *(const float4*)(src + idx);
        float4 v1 = *(const float4*)(src + idx + 4);
        short8 o;
        o[0] = f2bf(v0.x); o[1] = f2bf(v0.y); o[2] = f2bf(v0.z); o[3] = f2bf(v0.w);
        o[4] = f2bf(v1.x); o[5] = f2bf(v1.y); o[6] = f2bf(v1.z); o[7] = f2bf(v1.w);
        *(short8*)(dst + idx) = o;
        return;
    }
    int zi = (bx - 4352) * 1024 + t * 4;
    if (zi < 275456) *(float4*)(zero0 + zi) = (float4){0.f, 0.f, 0.f, 0.f};
}

// ---------------------------------------------------------------------------
// bf16 MFMA NT GEMM: C[M,N] = A[M,K] @ B[N,K]^T.  Tile TM x TN, 2x2 waves,
// 16x16x32 MFMA, BK=32, global_load_lds staging, double-buffered.
// ldk = row stride of A/B (elements); K = this launch's K extent.
// EPI: 1 proj (stats+colmeans, bf16 out), 2 +bias+resid f32 out,
//      4 MLP-up LN-fold + gelu bf16 out, 5 attn-out dual-write + rowstats,
//      6 K-split atomic f32 accumulate (bias added by blockIdx.z==0 only).
// ---------------------------------------------------------------------------
template <int TM, int TN, int EPI, bool OUT_BF16>
__global__ __launch_bounds__(256) void mfma_gemm_nt(
    const short* __restrict__ A, const short* __restrict__ B,
    void* __restrict__ C, int M, int N, int K, int ldk,
    const float* __restrict__ bias, const float* __restrict__ resid,
    short* __restrict__ C2, float* __restrict__ Sb,
    float* __restrict__ qgp, float* __restrict__ kgp) {
    constexpr int FI = TM / 32;
    constexpr int FJ = TN / 32;
    __shared__ short As[2][TM * 32];
    __shared__ short Bs[2][TN * 32];
    int t = threadIdx.x;
    int m0 = blockIdx.y * TM, n0 = blockIdx.x * TN;
    int w = t >> 6, lane = t & 63;
    int wm = (w & 1) * (TM / 2), wn = (w >> 1) * (TN / 2);
    if constexpr (EPI == 6) {  // K-split: offset into the K dimension
        A += (size_t)blockIdx.z * K;
        B += (size_t)blockIdx.z * K;
    }
    floatx4 acc[FI][FJ];
#pragma unroll
    for (int i = 0; i < FI; ++i)
#pragma unroll
        for (int j = 0; j < FJ; ++j) acc[i][j] = (floatx4){0.f, 0.f, 0.f, 0.f};

    int arow = t >> 2, acol = (t & 3) * 8;
    const short* Ag = A + (size_t)(m0 + arow) * ldk + acol;
    const short* Bg = B + (size_t)(n0 + arow) * ldk + acol;
    int ldsbase = w * 1024;  // bytes, wave-uniform

    auto stage = [&](int k0, int buf) {
#pragma unroll
        for (int u = 0; u < TM / 64; ++u)
            __builtin_amdgcn_global_load_lds(
                (const __attribute__((address_space(1))) void*)(Ag + (size_t)u * 64 * ldk + k0),
                (__attribute__((address_space(3))) void*)((char*)As[buf] + u * 4096 + ldsbase),
                16, 0, 0);
#pragma unroll
        for (int u = 0; u < TN / 64; ++u)
            __builtin_amdgcn_global_load_lds(
                (const __attribute__((address_space(1))) void*)(Bg + (size_t)u * 64 * ldk + k0),
                (__attribute__((address_space(3))) void*)((char*)Bs[buf] + u * 4096 + ldsbase),
                16, 0, 0);
    };

    stage(0, 0);
    __syncthreads();
    int nsteps = K >> 5;
    for (int ks = 0; ks < nsteps; ++ks) {
        int buf = ks & 1;
        if (ks + 1 < nsteps) stage((ks + 1) << 5, buf ^ 1);
        int krow = (lane >> 4) * 8;
        short8 af[FI], bf[FJ];
#pragma unroll
        for (int i = 0; i < FI; ++i)
            af[i] = *(const short8*)&As[buf][(wm + i * 16 + (lane & 15)) * 32 + krow];
#pragma unroll
        for (int j = 0; j < FJ; ++j)
            bf[j] = *(const short8*)&Bs[buf][(wn + j * 16 + (lane & 15)) * 32 + krow];
#pragma unroll
        for (int i = 0; i < FI; ++i)
#pragma unroll
            for (int j = 0; j < FJ; ++j)
                acc[i][j] = __builtin_amdgcn_mfma_f32_16x16x32_bf16(
                    af[i], bf[j], acc[i][j], 0, 0, 0);
        __syncthreads();
    }

    int col = lane & 15, rbase = (lane >> 4) * 4;
    if constexpr (EPI == 5) {
        // attn-out: v = acc + bias + resid; f32 C + bf16 C2 + rowstat atomics
#pragma unroll
        for (int i = 0; i < FI; ++i) {
#pragma unroll
            for (int r = 0; r < 4; ++r) {
                int grow = m0 + wm + i * 16 + rbase + r;
                float s = 0.f, sq = 0.f;
#pragma unroll
                for (int j = 0; j < FJ; ++j) {
                    int gcol = n0 + wn + j * 16 + col;
                    float vv = acc[i][j][r] + bias[gcol] +
                               resid[(size_t)grow * N + gcol];
                    ((float*)C)[(size_t)grow * N + gcol] = vv;
                    C2[(size_t)grow * N + gcol] = f2bf(vv);
                    s += vv;
                    sq += vv * vv;
                }
#pragma unroll
                for (int off = 1; off < 16; off <<= 1) {
                    s += __shfl_xor(s, off);
                    sq += __shfl_xor(sq, off);
                }
                if ((lane & 15) == 0) {
                    atomicAdd(&Sb[grow], s);
                    atomicAdd(&Sb[4096 + grow], sq);
                }
            }
        }
    } else if constexpr (EPI == 4) {
        // MLP-up LN-fold: v = rstd*acc + Bn + bup - m*rstd*Wg, gelu, bf16
#pragma unroll
        for (int i = 0; i < FI; ++i) {
#pragma unroll
            for (int r = 0; r < 4; ++r) {
                int grow = m0 + wm + i * 16 + rbase + r;
                float m = Sb[grow] * (1.f / 512.f);
                float rstd = rsqrtf(Sb[4096 + grow] * (1.f / 512.f) - m * m + EPS);
                float mrstd = m * rstd;
#pragma unroll
                for (int j = 0; j < FJ; ++j) {
                    int gcol = n0 + wn + j * 16 + col;
                    float vv = rstd * acc[i][j][r] + qgp[gcol] + bias[gcol] -
                               mrstd * kgp[gcol];
                    vv = 0.5f * vv * (1.f + erff(vv * 0.70710678118654752f));
                    ((short*)C)[(size_t)grow * N + gcol] = f2bf(vv);
                }
            }
        }
    } else if constexpr (EPI == 6) {
        // K-split accumulate: atomicAdd onto C (pre-holds resid); bias once
        bool addb = (blockIdx.z == 0);
#pragma unroll
        for (int i = 0; i < FI; ++i) {
#pragma unroll
            for (int j = 0; j < FJ; ++j) {
                int gcol = n0 + wn + j * 16 + col;
                float bz = addb ? bias[gcol] : 0.f;
#pragma unroll
                for (int r = 0; r < 4; ++r) {
                    int grow = m0 + wm + i * 16 + rbase + r;
                    atomicAdd(&((float*)C)[(size_t)grow * N + gcol],
                              acc[i][j][r] + bz);
                }
            }
        }
    } else {
#pragma unroll
        for (int i = 0; i < FI; ++i) {
#pragma unroll
            for (int j = 0; j < FJ; ++j) {
                int gcol = n0 + wn + j * 16 + col;
#pragma unroll
                for (int r = 0; r < 4; ++r) {
                    int grow = m0 + wm + i * 16 + rbase + r;
                    float v = acc[i][j][r];
                    if (EPI == 2) v += bias[gcol] + resid[(size_t)grow * N + gcol];
                    if (OUT_BF16)
                        ((short*)C)[(size_t)grow * N + gcol] = f2bf(v);
                    else
                        ((float*)C)[(size_t)grow * N + gcol] = v;
                }
            }
        }
    }

    // EPI==1: fused per-(head,row) stats + per-head column sums for fq/fk.
    if constexpr (EPI == 1) {
        if (m0 < 8192) {
            int tensor = m0 >> 12;  // 0=fq, 1=fk
            float* Sbase = Sb + (size_t)tensor * 98304;
            float* dst = tensor ? kgp : qgp;
            int head = (n0 + wn) >> 6;
            int rowbase = (m0 & 4095) + wm;
#pragma unroll
            for (int i = 0; i < FI; ++i) {
#pragma unroll
                for (int r = 0; r < 4; ++r) {
                    float s = 0.f, sq = 0.f;
#pragma unroll
                    for (int j = 0; j < FJ; ++j) {
                        float vv = acc[i][j][r];
                        s += vv;
                        sq += vv * vv;
                    }
#pragma unroll
                    for (int off = 1; off < 16; off <<= 1) {
                        s += __shfl_xor(s, off);
                        sq += __shfl_xor(sq, off);
                    }
                    if ((lane & 15) == 0) {
                        int row = rowbase + i * 16 + rbase + r;
                        int idx = head * ROWS + row;
                        float m = s * (1.f / 64.f);
                        Sbase[idx] = m;
                        Sbase[32768 + idx] = rsqrtf(sq);
                        Sbase[65536 + idx] = (sq - 64.f * m * m) * (1.f / 63.f);
                    }
                }
            }
            float cs[FJ];
#pragma unroll
            for (int j = 0; j < FJ; ++j) {
                float s = 0.f;
#pragma unroll
                for (int i = 0; i < FI; ++i)
#pragma unroll
                    for (int r = 0; r < 4; ++r) s += acc[i][j][r];
                s += __shfl_xor(s, 16);
                s += __shfl_xor(s, 32);
                cs[j] = s;
            }
            if (lane < 16) {
#pragma unroll
                for (int j = 0; j < FJ; ++j)
                    atomicAdd(&dst[head * 64 + j * 16 + lane], cs[j] * (1.f / 4096.f));
            }
        }
    }
}

// ---------------------------------------------------------------------------
// Transpose/convert for kside GEMM + skv/smk + policy MLP. Inputs bf16 fqkv.
// grid (32 hb, 9, 2). y<8: transpose chunk of 128 rows.
//   z==0: fk -> fkTall rows [0,64)=fk^T, [64,128)=(rnk*fk)^T  (bf16)
//   z==1: fv -> fvT [64][1024] bf16, plus skv/smk f32 atomics into Sv.
// y==8 && z==0 && hb<8: policy MLP for head hb.
// ---------------------------------------------------------------------------
__global__ __launch_bounds__(256) void tr_kv(
    const short* __restrict__ fkb, const short* __restrict__ fvb,
    const float* __restrict__ rnk, const float* __restrict__ kvv,
    const float* __restrict__ mkm, short* __restrict__ fkTall,
    short* __restrict__ fvT, float* __restrict__ Sv,
    const float* __restrict__ qg, const float* __restrict__ kg,
    const float* __restrict__ W1, const float* __restrict__ b1,
    const float* __restrict__ g, const float* __restrict__ bb,
    const float* __restrict__ W2, const float* __restrict__ b2,
    float* __restrict__ wmix) {
    int hb = blockIdx.x;
    int t = threadIdx.x;
    if (blockIdx.y == 8) {  // policy MLP slice
        if (blockIdx.z != 0 || hb >= 8 || t >= 64) return;
        int h = hb, j = t;
        float acc = 0.f;
        const float* w1r = W1 + j * 128;
        for (int i = 0; i < 64; ++i) acc += qg[h * 64 + i] * w1r[i];
        for (int i = 0; i < 64; ++i) acc += kg[h * 64 + i] * w1r[64 + i];
        acc += b1[j];
        float s = acc, sq = acc * acc;
#pragma unroll
        for (int off = 32; off; off >>= 1) {
            s += __shfl_xor(s, off);
            sq += __shfl_xor(sq, off);
        }
        float m = s * (1.f / 64.f);
        float var = sq * (1.f / 64.f) - m * m;
        float xh = (acc - m) * rsqrtf(var + EPS) * g[j] + bb[j];
        float r = fmaxf(xh, 0.f);
        float l[3];
#pragma unroll
        for (int c = 0; c < 3; ++c) {
            float p = r * W2[c * 64 + j];
#pragma unroll
            for (int off = 32; off; off >>= 1) p += __shfl_xor(p, off);
            l[c] = p + b2[c];
        }
        if (j == 0) {
            float mx = fmaxf(l[0], fmaxf(l[1], l[2]));
            float e0 = expf(l[0] - mx), e1 = expf(l[1] - mx), e2 = expf(l[2] - mx);
            float inv = 1.f / (e0 + e1 + e2);
            wmix[h * 3 + 0] = e0 * inv;
            wmix[h * 3 + 1] = e1 * inv;
            wmix[h * 3 + 2] = e2 * inv;
        }
        return;
    }
    int chunk = blockIdx.y;
    int tensor = blockIdx.z;
    int h = hb >> 2, b = hb & 3;
    __shared__ float tile[32][68];
    __shared__ float sc[32], sc2[32];
    const short* src = tensor ? fvb : fkb;
    float skv_acc = 0.f, smk_acc = 0.f;
    int e = t & 63, qd = t >> 6;
    int d = t >> 2, mg = (t & 3) * 8;
    for (int s4 = 0; s4 < 4; ++s4) {
        int m0 = chunk * 128 + s4 * 32;
        __syncthreads();
        {
            int idx = t * 8;
            int mm = idx >> 6, dd = idx & 63;
            short8 sv = *(const short8*)&src[(size_t)(b * 1024 + m0 + mm) * 512 + h * 64 + dd];
#pragma unroll
            for (int i = 0; i < 8; ++i) tile[mm][dd + i] = bf2f(sv[i]);
        }
        if (t < 32) {
            int sidx = h * ROWS + b * 1024 + m0 + t;
            if (tensor == 0) {
                sc[t] = rnk[sidx];
            } else {
                sc[t] = kvv[sidx];
                sc2[t] = mkm[sidx];
            }
        }
        __syncthreads();
        if (tensor == 0) {
            short8 o1, o2;
#pragma unroll
            for (int i = 0; i < 8; ++i) {
                float vv = tile[mg + i][d];
                o1[i] = f2bf(vv);
                o2[i] = f2bf(vv * sc[mg + i]);
            }
            *(short8*)&fkTall[((size_t)hb * 128 + d) * 1024 + m0 + mg] = o1;
            *(short8*)&fkTall[((size_t)hb * 128 + 64 + d) * 1024 + m0 + mg] = o2;
        } else {
            short8 o1;
#pragma unroll
            for (int i = 0; i < 8; ++i) o1[i] = f2bf(tile[mg + i][d]);
            *(short8*)&fvT[((size_t)hb * 64 + d) * 1024 + m0 + mg] = o1;
#pragma unroll
            for (int i = 0; i < 8; ++i) {
                float vv = tile[qd * 8 + i][e];
                skv_acc += sc[qd * 8 + i] * vv;
                smk_acc += sc2[qd * 8 + i] * vv;
            }
        }
    }
    if (tensor == 1) {
        atomicAdd(&Sv[hb * 128 + e], skv_acc);
        atomicAdd(&Sv[hb * 128 + 64 + e], smk_acc);
    }
}

// ---------------------------------------------------------------------------
// Batched kside GEMM: per (hb, half): C[64,64] += A[64,1024] @ B[64,1024]^T
// grid (32, 2, 4 ksplit), double-buffered; atomicAdd into pre-zeroed Mnew.
// ---------------------------------------------------------------------------
__global__ __launch_bounds__(256) void kside_gemm(
    const short* __restrict__ fkTall, const short* __restrict__ fvT,
    float* __restrict__ Mnew) {
    int hb = blockIdx.x, half = blockIdx.y, kz = blockIdx.z;
    const short* A = fkTall + ((size_t)hb * 128 + half * 64) * 1024 + kz * 256;
    const short* B = fvT + (size_t)hb * 64 * 1024 + kz * 256;
    __shared__ short As[2][64 * 32];
    __shared__ short Bs[2][64 * 32];
    int t = threadIdx.x;
    int w = t >> 6, lane = t & 63;
    int wm = (w & 1) * 32, wn = (w >> 1) * 32;
    floatx4 acc[2][2];
#pragma unroll
    for (int i = 0; i < 2; ++i)
#pragma unroll
        for (int j = 0; j < 2; ++j) acc[i][j] = (floatx4){0.f, 0.f, 0.f, 0.f};
    int arow = t >> 2, acol = (t & 3) * 8;
    const short* Ag = A + (size_t)arow * 1024 + acol;
    const short* Bg = B + (size_t)arow * 1024 + acol;
    int ldsbase = w * 1024;  // bytes

    auto stage = [&](int k0, int buf) {
        __builtin_amdgcn_global_load_lds(
            (const __attribute__((address_space(1))) void*)(Ag + k0),
            (__attribute__((address_space(3))) void*)((char*)As[buf] + ldsbase), 16, 0, 0);
        __builtin_amdgcn_global_load_lds(
            (const __attribute__((address_space(1))) void*)(Bg + k0),
            (__attribute__((address_space(3))) void*)((char*)Bs[buf] + ldsbase), 16, 0, 0);
    };

    stage(0, 0);
    __syncthreads();
    for (int ks = 0; ks < 8; ++ks) {
        int buf = ks & 1;
        if (ks + 1 < 8) stage((ks + 1) << 5, buf ^ 1);
        int krow = (lane >> 4) * 8;
        short8 af[2], bf[2];
#pragma unroll
        for (int i = 0; i < 2; ++i)
            af[i] = *(const short8*)&As[buf][(wm + i * 16 + (lane & 15)) * 32 + krow];
#pragma unroll
        for (int j = 0; j < 2; ++j)
            bf[j] = *(const short8*)&Bs[buf][(wn + j * 16 + (lane & 15)) * 32 + krow];
#pragma unroll
        for (int i = 0; i < 2; ++i)
#pragma unroll
            for (int j = 0; j < 2; ++j)
                acc[i][j] = __builtin_amdgcn_mfma_f32_16x16x32_bf16(
                    af[i], bf[j], acc[i][j], 0, 0, 0);
        __syncthreads();
    }
    int col = lane & 15, rbase = (lane >> 4) * 4;
    float* Cb = Mnew + (size_t)hb * 8192 + half * 4096;
#pragma unroll
    for (int i = 0; i < 2; ++i)
#pragma unroll
        for (int j = 0; j < 2; ++j)
#pragma unroll
            for (int r = 0; r < 4; ++r)
                atomicAdd(&Cb[(wm + i * 16 + rbase + r) * 64 + wn + j * 16 + col],
                          acc[i][j][r]);
}

// ---------------------------------------------------------------------------
// Q-side apply, 64 rows per block. grid (16, 32). fq input bf16.
// Mnew layout: [hb][0:4096]=M2, [4096:8192]=M1.  Sv: [hb][0:64]=skv,[64:128]=smk.
// ---------------------------------------------------------------------------
__global__ __launch_bounds__(256) void qside(
    const short* __restrict__ fqb, const float* __restrict__ Mnew,
    const float* __restrict__ Sv, const float* __restrict__ rnq,
    const float* __restrict__ mq, const float* __restrict__ qv,
    const float* __restrict__ wmix, short* __restrict__ attn_out) {
    int ntile = blockIdx.x, hb = blockIdx.y;
    int h = hb >> 2, b = hb & 3;
    __shared__ float M1s[4096], M2s[4096], fqt[4096];
    __shared__ float Skvs[64], Smks[64], rnqs[64], mqs[64], qvs[64];
    int t = threadIdx.x;
    const float* base = Mnew + (size_t)hb * 8192;
#pragma unroll
    for (int u = 0; u < 4; ++u) {
        int idx = t * 4 + u * 1024;
        *(float4*)&M2s[idx] = *(const float4*)&base[idx];
        *(float4*)&M1s[idx] = *(const float4*)&base[4096 + idx];
    }
    int n0 = ntile * 64;
#pragma unroll
    for (int u = 0; u < 2; ++u) {
        int idx = t * 8 + u * 2048;
        int r = idx >> 6, d = idx & 63;
        short8 sv = *(const short8*)&fqb[(size_t)(b * 1024 + n0 + r) * 512 + h * 64 + d];
#pragma unroll
        for (int i = 0; i < 8; ++i) fqt[idx + i] = bf2f(sv[i]);
    }
    if (t < 64) {
        Skvs[t] = Sv[hb * 128 + t];
        Smks[t] = Sv[hb * 128 + 64 + t];
        int sidx = h * ROWS + b * 1024 + n0 + t;
        rnqs[t] = rnq[sidx];
        mqs[t] = mq[sidx];
        qvs[t] = qv[sidx];
    }
    __syncthreads();
    float cw = wmix[h * 3 + 0], covw = wmix[h * 3 + 1], vw = wmix[h * 3 + 2];
    int e = t & 63, rq = t >> 6;
    float a1[16] = {}, a2[16] = {};
    for (int d4 = 0; d4 < 64; d4 += 4) {
        float md1[4], md2[4];
#pragma unroll
        for (int dd = 0; dd < 4; ++dd) {
            md1[dd] = M1s[(d4 + dd) * 64 + e];
            md2[dd] = M2s[(d4 + dd) * 64 + e];
        }
#pragma unroll
        for (int i = 0; i < 16; ++i) {
            float4 f = *(const float4*)&fqt[(rq * 16 + i) * 64 + d4];
            a1[i] += f.x * md1[0] + f.y * md1[1] + f.z * md1[2] + f.w * md1[3];
            a2[i] += f.x * md2[0] + f.y * md2[1] + f.z * md2[2] + f.w * md2[3];
        }
    }
    float c2 = covw * (1.f / 64.f), c3 = vw * (1.f / 64.f);
#pragma unroll
    for (int i = 0; i < 16; ++i) {
        int rr = rq * 16 + i;
        float v = cw * rnqs[rr] * a1[i] + c2 * a2[i] + c3 * qvs[rr] * Skvs[e] -
                  covw * mqs[rr] * Smks[e];
        attn_out[(size_t)(b * 1024 + n0 + rr) * 512 + h * 64 + e] = f2bf(v);
    }
}

// ---------------------------------------------------------------------------
extern "C" void kernel_launch(void* const* d_in, const int* in_sizes, int n_in,
                              void* d_out, int out_size, void* d_ws, size_t ws_size,
                              hipStream_t stream) {
    const float* q = (const float*)d_in[0];
    const float* k = (const float*)d_in[1];
    const float* v = (const float*)d_in[2];
    const float* Win = (const float*)d_in[3];
    const float* Wout = (const float*)d_in[4];
    const float* bout = (const float*)d_in[5];
    const float* g1 = (const float*)d_in[6];
    const float* b1n = (const float*)d_in[7];
    const float* g2 = (const float*)d_in[8];
    const float* b2n = (const float*)d_in[9];
    const float* Wup = (const float*)d_in[10];
    const float* bup = (const float*)d_in[11];
    const float* Wdn = (const float*)d_in[12];
    const float* bdn = (const float*)d_in[13];
    const float* wpW1 = (const float*)d_in[14];
    const float* wpb1 = (const float*)d_in[15];
    const float* wpg = (const float*)d_in[16];
    const float* wpb = (const float*)d_in[17];
    const float* wpW2 = (const float*)d_in[18];
    const float* wpb2 = (const float*)d_in[19];
    float* out = (float*)d_out;

    float* wsf = (float*)d_ws;
    // bf16 fqkv [12288][512]: fq rows 0-4095, fk 4096-8191, fv 8192-12287
    short* fqkv = (short*)wsf;                    // [0, 3145728) floats
    short* fkb = fqkv + (size_t)4096 * 512;
    short* fvb = fqkv + (size_t)8192 * 512;
    short* qkvln = (short*)(wsf + 3145728);       // [3145728, 6291456) floats
    short* hmid = (short*)wsf;                    // [0, 4194304) floats (step 7)
    short* fkTall = (short*)(wsf + 4194304);      // [4194304, 6291456) floats
    short* attnbf = (short*)(wsf + 4194304);      // reuses fkTall (step 5+)
    short* fvT = (short*)(wsf + 6291456);         // [6291456, 7340032) floats
    short* q2bf = (short*)(wsf + 7340032);        // [7340032, 8388608) floats
    short* Winbf = (short*)(wsf + 8388608);
    short* Woutbf = (short*)(wsf + 8388608 + 131072);
    short* Wupbf = (short*)(wsf + 8388608 + 262144);
    short* Wdnbf = (short*)(wsf + 8388608 + 262144 + 524288);
    float* S = wsf + 9699328;        // [2][3][32768] head stats
    float* qg = S + 196608;          // 512   (zero region start)
    float* kg = qg + 512;            // 512
    float* Mnew = kg + 512;          // 262144
    float* Sv = Mnew + 262144;       // 4096
    float* rowstats = Sv + 4096;     // 8192 (rowsum 4096 + rowsumsq 4096)
    float* wmix = rowstats + 8192;   // 32  (not zeroed)
    float* Bn = wmix + 32;           // 2048 (not zeroed)
    float* Wg = Bn + 2048;           // 2048 (not zeroed)
    float* mqS = S, *rnqS = S + 32768, *qvS = S + 65536;
    float* mkS = S + 98304, *rnkS = S + 131072, *kvS = S + 163840;

    // 1. fused prep: LN(q/k/v)->bf16, weights->bf16 (+Bn/Wg), zero stats
    prep<<<4621, 256, 0, stream>>>(q, k, v, g1, b1n, qkvln,
                                   Win, Wout, Wup, Wdn,
                                   Winbf, Woutbf, Wupbf, Wdnbf,
                                   g2, b2n, Bn, Wg, qg);

    // 2. stacked projection -> bf16 fqkv + fused head-stats/colmeans
    mfma_gemm_nt<64, 128, 1, true><<<dim3(4, 192), 256, 0, stream>>>(
        qkvln, Winbf, fqkv, 12288, 512, 512, 512, nullptr, nullptr, nullptr,
        S, qg, kg);

    // 3. transpose/convert K,V for kside GEMM + skv/smk + policy MLP
    tr_kv<<<dim3(32, 9, 2), 256, 0, stream>>>(fkb, fvb, rnkS, kvS, mkS,
                                              fkTall, fvT, Sv,
                                              qg, kg, wpW1, wpb1, wpg, wpb,
                                              wpW2, wpb2, wmix);

    // 4. batched MFMA kside GEMM -> Mnew (atomic, 4-way K-split)
    kside_gemm<<<dim3(32, 2, 4), 256, 0, stream>>>(fkTall, fvT, Mnew);

    // 5. Q-side apply
    qside<<<dim3(16, 32), 256, 0, stream>>>(fqkv, Mnew, Sv, rnqS, mqS, qvS,
                                            wmix, attnbf);

    // 6. q2 = q + attn @ Wout^T + bout -> out(f32) + q2bf(bf16) + rowstats
    mfma_gemm_nt<64, 64, 5, false><<<dim3(8, 64), 256, 0, stream>>>(
        attnbf, Woutbf, out, 4096, 512, 512, 512, bout, q, q2bf,
        rowstats, nullptr, nullptr);

    // 7. MLP-up with LN folded: h = gelu(rstd*(q2@Wup'^T) + Bn + bup - m*rstd*Wg)
    //    128x128 tile: 512 blocks = 2/CU, 16 MFMA : 8 ds_read per wave-K-step
    mfma_gemm_nt<128, 128, 4, true><<<dim3(16, 32), 256, 0, stream>>>(
        q2bf, Wupbf, hmid, 4096, 2048, 512, 512, bup, nullptr, nullptr,
        rowstats, Bn, Wg);

    // 8. out(q2) += h@Wdn^T + bdn   (K-split 2: grid (4,64,2) = 512 blocks)
    mfma_gemm_nt<64, 128, 6, false><<<dim3(4, 64, 2), 256, 0, stream>>>(
        hmid, Wdnbf, out, 4096, 512, 1024, 2048, bdn, nullptr, nullptr,
        nullptr, nullptr, nullptr);
}

// Round 7
// 232.645 us; speedup vs baseline: 1.0136x; 1.0136x over previous
//
#include <hip/hip_runtime.h>
#include <math.h>

#define EPS 1e-5f
#define ROWS 4096  // B*N

typedef __attribute__((ext_vector_type(8))) short short8;
typedef __attribute__((ext_vector_type(4))) float floatx4;

__device__ inline short f2bf(float f) {
    unsigned u = __builtin_bit_cast(unsigned, f);
    unsigned r = (u + 0x7fffu + ((u >> 16) & 1u)) >> 16;
    return (short)r;
}
__device__ inline float bf2f(short s) {
    return __builtin_bit_cast(float, (unsigned)(unsigned short)s << 16);
}

// ---------------------------------------------------------------------------
// Fused prep: blocks [0,3072): LN(q/k/v)->bf16 ; [3072,4352): weights->bf16
// (Wup gets g2-scaled + per-row Bn/Wg dots) ; [4352,4621): zero stats buffers.
// ---------------------------------------------------------------------------
__global__ __launch_bounds__(256) void prep(
    const float* __restrict__ q, const float* __restrict__ k,
    const float* __restrict__ v, const float* __restrict__ g,
    const float* __restrict__ bb, short* __restrict__ qkvout,
    const float* __restrict__ w0, const float* __restrict__ w1,
    const float* __restrict__ w2, const float* __restrict__ w3,
    short* __restrict__ o0, short* __restrict__ o1,
    short* __restrict__ o2, short* __restrict__ o3,
    const float* __restrict__ g2, const float* __restrict__ b2n,
    float* __restrict__ Bn, float* __restrict__ Wg,
    float* __restrict__ zero0) {
    int bx = blockIdx.x;
    int t = threadIdx.x;
    if (bx < 3072) {  // layernorm of q/k/v, 4 rows per block
        int tensor = bx >> 10;
        int xb = bx & 1023;
        const float* x = tensor == 0 ? q : (tensor == 1 ? k : v);
        int row = xb * 4 + (t >> 6);
        int col = (t & 63) * 8;
        const float* xr = x + (size_t)row * 512 + col;
        float4 v0 = *(const float4*)xr;
        float4 v1 = *(const float4*)(xr + 4);
        float s = v0.x + v0.y + v0.z + v0.w + v1.x + v1.y + v1.z + v1.w;
        float sq = v0.x * v0.x + v0.y * v0.y + v0.z * v0.z + v0.w * v0.w +
                   v1.x * v1.x + v1.y * v1.y + v1.z * v1.z + v1.w * v1.w;
#pragma unroll
        for (int off = 32; off; off >>= 1) {
            s += __shfl_xor(s, off);
            sq += __shfl_xor(sq, off);
        }
        float m = s * (1.f / 512.f);
        float rstd = rsqrtf(sq * (1.f / 512.f) - m * m + EPS);
        float4 g0 = *(const float4*)(g + col);
        float4 g1 = *(const float4*)(g + col + 4);
        float4 b0 = *(const float4*)(bb + col);
        float4 b1 = *(const float4*)(bb + col + 4);
        short8 o;
        o[0] = f2bf((v0.x - m) * rstd * g0.x + b0.x);
        o[1] = f2bf((v0.y - m) * rstd * g0.y + b0.y);
        o[2] = f2bf((v0.z - m) * rstd * g0.z + b0.z);
        o[3] = f2bf((v0.w - m) * rstd * g0.w + b0.w);
        o[4] = f2bf((v1.x - m) * rstd * g1.x + b1.x);
        o[5] = f2bf((v1.y - m) * rstd * g1.y + b1.y);
        o[6] = f2bf((v1.z - m) * rstd * g1.z + b1.z);
        o[7] = f2bf((v1.w - m) * rstd * g1.w + b1.w);
        *(short8*)(qkvout + (size_t)(tensor * 4096 + row) * 512 + col) = o;
        return;
    }
    if (bx < 4352) {  // weight conversion, 2048 elems per block
        int wb = bx - 3072;
        if (wb >= 256 && wb < 768) {
            // Wup: scale by g2, plus per-row dots Bn = b2n.Wrow, Wg = g2.Wrow
            int base = wb - 256;
            int idx = base * 2048 + t * 8;
            int n = idx >> 9, c = idx & 511;
            float4 v0 = *(const float4*)(w2 + idx);
            float4 v1 = *(const float4*)(w2 + idx + 4);
            float4 ga = *(const float4*)(g2 + c);
            float4 gb = *(const float4*)(g2 + c + 4);
            float4 ba = *(const float4*)(b2n + c);
            float4 bbv = *(const float4*)(b2n + c + 4);
            short8 o;
            o[0] = f2bf(ga.x * v0.x); o[1] = f2bf(ga.y * v0.y);
            o[2] = f2bf(ga.z * v0.z); o[3] = f2bf(ga.w * v0.w);
            o[4] = f2bf(gb.x * v1.x); o[5] = f2bf(gb.y * v1.y);
            o[6] = f2bf(gb.z * v1.z); o[7] = f2bf(gb.w * v1.w);
            *(short8*)(o2 + idx) = o;
            float bn = ba.x * v0.x + ba.y * v0.y + ba.z * v0.z + ba.w * v0.w +
                       bbv.x * v1.x + bbv.y * v1.y + bbv.z * v1.z + bbv.w * v1.w;
            float wg = ga.x * v0.x + ga.y * v0.y + ga.z * v0.z + ga.w * v0.w +
                       gb.x * v1.x + gb.y * v1.y + gb.z * v1.z + gb.w * v1.w;
#pragma unroll
            for (int off = 32; off; off >>= 1) {
                bn += __shfl_xor(bn, off);
                wg += __shfl_xor(wg, off);
            }
            if ((t & 63) == 0) {
                Bn[n] = bn;
                Wg[n] = wg;
            }
            return;
        }
        const float* src;
        short* dst;
        int base;
        if (wb < 128) { src = w0; dst = o0; base = wb; }
        else if (wb < 256) { src = w1; dst = o1; base = wb - 128; }
        else { src = w3; dst = o3; base = wb - 768; }
        int idx = base * 2048 + t * 8;
        float4 v0 = *(const float4*)(src + idx);
        float4 v1 = *(const float4*)(src + idx + 4);
        short8 o;
        o[0] = f2bf(v0.x); o[1] = f2bf(v0.y); o[2] = f2bf(v0.z); o[3] = f2bf(v0.w);
        o[4] = f2bf(v1.x); o[5] = f2bf(v1.y); o[6] = f2bf(v1.z); o[7] = f2bf(v1.w);
        *(short8*)(dst + idx) = o;
        return;
    }
    int zi = (bx - 4352) * 1024 + t * 4;
    if (zi < 275456) *(float4*)(zero0 + zi) = (float4){0.f, 0.f, 0.f, 0.f};
}

// ---------------------------------------------------------------------------
// bf16 MFMA NT GEMM: C[M,N] = A[M,K] @ B[N,K]^T.  Tile TM x TN, 2x2 waves,
// 16x16x32 MFMA, BK=32, global_load_lds staging, double-buffered.
// ldk = row stride of A/B (elements); K = K extent.
// EPI: 1 proj (stats+colmeans, bf16 out), 2 +bias+resid f32 out,
//      4 MLP-up LN-fold + gelu bf16 out, 5 attn-out dual-write + rowstats.
// ---------------------------------------------------------------------------
template <int TM, int TN, int EPI, bool OUT_BF16>
__global__ __launch_bounds__(256) void mfma_gemm_nt(
    const short* __restrict__ A, const short* __restrict__ B,
    void* __restrict__ C, int M, int N, int K, int ldk,
    const float* __restrict__ bias, const float* __restrict__ resid,
    short* __restrict__ C2, float* __restrict__ Sb,
    float* __restrict__ qgp, float* __restrict__ kgp) {
    constexpr int FI = TM / 32;
    constexpr int FJ = TN / 32;
    __shared__ short As[2][TM * 32];
    __shared__ short Bs[2][TN * 32];
    int t = threadIdx.x;
    int m0 = blockIdx.y * TM, n0 = blockIdx.x * TN;
    int w = t >> 6, lane = t & 63;
    int wm = (w & 1) * (TM / 2), wn = (w >> 1) * (TN / 2);
    floatx4 acc[FI][FJ];
#pragma unroll
    for (int i = 0; i < FI; ++i)
#pragma unroll
        for (int j = 0; j < FJ; ++j) acc[i][j] = (floatx4){0.f, 0.f, 0.f, 0.f};

    int arow = t >> 2, acol = (t & 3) * 8;
    const short* Ag = A + (size_t)(m0 + arow) * ldk + acol;
    const short* Bg = B + (size_t)(n0 + arow) * ldk + acol;
    int ldsbase = w * 1024;  // bytes, wave-uniform

    auto stage = [&](int k0, int buf) {
#pragma unroll
        for (int u = 0; u < TM / 64; ++u)
            __builtin_amdgcn_global_load_lds(
                (const __attribute__((address_space(1))) void*)(Ag + (size_t)u * 64 * ldk + k0),
                (__attribute__((address_space(3))) void*)((char*)As[buf] + u * 4096 + ldsbase),
                16, 0, 0);
#pragma unroll
        for (int u = 0; u < TN / 64; ++u)
            __builtin_amdgcn_global_load_lds(
                (const __attribute__((address_space(1))) void*)(Bg + (size_t)u * 64 * ldk + k0),
                (__attribute__((address_space(3))) void*)((char*)Bs[buf] + u * 4096 + ldsbase),
                16, 0, 0);
    };

    stage(0, 0);
    __syncthreads();
    int nsteps = K >> 5;
    for (int ks = 0; ks < nsteps; ++ks) {
        int buf = ks & 1;
        if (ks + 1 < nsteps) stage((ks + 1) << 5, buf ^ 1);
        int krow = (lane >> 4) * 8;
        short8 af[FI], bf[FJ];
#pragma unroll
        for (int i = 0; i < FI; ++i)
            af[i] = *(const short8*)&As[buf][(wm + i * 16 + (lane & 15)) * 32 + krow];
#pragma unroll
        for (int j = 0; j < FJ; ++j)
            bf[j] = *(const short8*)&Bs[buf][(wn + j * 16 + (lane & 15)) * 32 + krow];
#pragma unroll
        for (int i = 0; i < FI; ++i)
#pragma unroll
            for (int j = 0; j < FJ; ++j)
                acc[i][j] = __builtin_amdgcn_mfma_f32_16x16x32_bf16(
                    af[i], bf[j], acc[i][j], 0, 0, 0);
        __syncthreads();
    }

    int col = lane & 15, rbase = (lane >> 4) * 4;
    if constexpr (EPI == 5) {
        // attn-out: v = acc + bias + resid; f32 C + bf16 C2 + rowstat atomics
#pragma unroll
        for (int i = 0; i < FI; ++i) {
#pragma unroll
            for (int r = 0; r < 4; ++r) {
                int grow = m0 + wm + i * 16 + rbase + r;
                float s = 0.f, sq = 0.f;
#pragma unroll
                for (int j = 0; j < FJ; ++j) {
                    int gcol = n0 + wn + j * 16 + col;
                    float vv = acc[i][j][r] + bias[gcol] +
                               resid[(size_t)grow * N + gcol];
                    ((float*)C)[(size_t)grow * N + gcol] = vv;
                    C2[(size_t)grow * N + gcol] = f2bf(vv);
                    s += vv;
                    sq += vv * vv;
                }
#pragma unroll
                for (int off = 1; off < 16; off <<= 1) {
                    s += __shfl_xor(s, off);
                    sq += __shfl_xor(sq, off);
                }
                if ((lane & 15) == 0) {
                    atomicAdd(&Sb[grow], s);
                    atomicAdd(&Sb[4096 + grow], sq);
                }
            }
        }
    } else if constexpr (EPI == 4) {
        // MLP-up LN-fold: v = rstd*acc + Bn + bup - m*rstd*Wg, gelu, bf16
#pragma unroll
        for (int i = 0; i < FI; ++i) {
#pragma unroll
            for (int r = 0; r < 4; ++r) {
                int grow = m0 + wm + i * 16 + rbase + r;
                float m = Sb[grow] * (1.f / 512.f);
                float rstd = rsqrtf(Sb[4096 + grow] * (1.f / 512.f) - m * m + EPS);
                float mrstd = m * rstd;
#pragma unroll
                for (int j = 0; j < FJ; ++j) {
                    int gcol = n0 + wn + j * 16 + col;
                    float vv = rstd * acc[i][j][r] + qgp[gcol] + bias[gcol] -
                               mrstd * kgp[gcol];
                    vv = 0.5f * vv * (1.f + erff(vv * 0.70710678118654752f));
                    ((short*)C)[(size_t)grow * N + gcol] = f2bf(vv);
                }
            }
        }
    } else {
#pragma unroll
        for (int i = 0; i < FI; ++i) {
#pragma unroll
            for (int j = 0; j < FJ; ++j) {
                int gcol = n0 + wn + j * 16 + col;
#pragma unroll
                for (int r = 0; r < 4; ++r) {
                    int grow = m0 + wm + i * 16 + rbase + r;
                    float v = acc[i][j][r];
                    if (EPI == 2) v += bias[gcol] + resid[(size_t)grow * N + gcol];
                    if (OUT_BF16)
                        ((short*)C)[(size_t)grow * N + gcol] = f2bf(v);
                    else
                        ((float*)C)[(size_t)grow * N + gcol] = v;
                }
            }
        }
    }

    // EPI==1: fused per-(head,row) stats + per-head column sums for fq/fk.
    if constexpr (EPI == 1) {
        if (m0 < 8192) {
            int tensor = m0 >> 12;  // 0=fq, 1=fk
            float* Sbase = Sb + (size_t)tensor * 98304;
            float* dst = tensor ? kgp : qgp;
            int head = (n0 + wn) >> 6;
            int rowbase = (m0 & 4095) + wm;
#pragma unroll
            for (int i = 0; i < FI; ++i) {
#pragma unroll
                for (int r = 0; r < 4; ++r) {
                    float s = 0.f, sq = 0.f;
#pragma unroll
                    for (int j = 0; j < FJ; ++j) {
                        float vv = acc[i][j][r];
                        s += vv;
                        sq += vv * vv;
                    }
#pragma unroll
                    for (int off = 1; off < 16; off <<= 1) {
                        s += __shfl_xor(s, off);
                        sq += __shfl_xor(sq, off);
                    }
                    if ((lane & 15) == 0) {
                        int row = rowbase + i * 16 + rbase + r;
                        int idx = head * ROWS + row;
                        float m = s * (1.f / 64.f);
                        Sbase[idx] = m;
                        Sbase[32768 + idx] = rsqrtf(sq);
                        Sbase[65536 + idx] = (sq - 64.f * m * m) * (1.f / 63.f);
                    }
                }
            }
            float cs[FJ];
#pragma unroll
            for (int j = 0; j < FJ; ++j) {
                float s = 0.f;
#pragma unroll
                for (int i = 0; i < FI; ++i)
#pragma unroll
                    for (int r = 0; r < 4; ++r) s += acc[i][j][r];
                s += __shfl_xor(s, 16);
                s += __shfl_xor(s, 32);
                cs[j] = s;
            }
            if (lane < 16) {
#pragma unroll
                for (int j = 0; j < FJ; ++j)
                    atomicAdd(&dst[head * 64 + j * 16 + lane], cs[j] * (1.f / 4096.f));
            }
        }
    }
}

// ---------------------------------------------------------------------------
// Fused kside: in-LDS transpose + batched MFMA GEMM + skv/smk + policy MLP.
// grid (33, 4).  x<32: block (hb, kz) computes partial over m-slice kz*256:
//   Mnew[hb][0:4096]  += fk^T @ fv        (plain,  M2)
//   Mnew[hb][4096:]   += (rnk*fk)^T @ fv  (scaled, M1)
//   Sv[hb][0:64] += kvv.fv slice ; Sv[hb][64:128] += mk.fv slice
// x==32: policy MLP, 2 heads per block (waves 0/1), h = y*2 + wave.
// ---------------------------------------------------------------------------
__global__ __launch_bounds__(256) void kside_fused(
    const short* __restrict__ fkb, const short* __restrict__ fvb,
    const float* __restrict__ rnk, const float* __restrict__ kvv,
    const float* __restrict__ mkm, float* __restrict__ Mnew,
    float* __restrict__ Sv,
    const float* __restrict__ qg, const float* __restrict__ kg,
    const float* __restrict__ W1, const float* __restrict__ b1,
    const float* __restrict__ g, const float* __restrict__ bb,
    const float* __restrict__ W2, const float* __restrict__ b2,
    float* __restrict__ wmix) {
    int t = threadIdx.x;
    if (blockIdx.x == 32) {  // policy MLP: heads y*2 + {0,1} on waves 0,1
        int wv = t >> 6;
        if (wv >= 2) return;
        int h = blockIdx.y * 2 + wv;
        int j = t & 63;
        float acc = 0.f;
        const float* w1r = W1 + j * 128;
        for (int i = 0; i < 64; ++i) acc += qg[h * 64 + i] * w1r[i];
        for (int i = 0; i < 64; ++i) acc += kg[h * 64 + i] * w1r[64 + i];
        acc += b1[j];
        float s = acc, sq = acc * acc;
#pragma unroll
        for (int off = 32; off; off >>= 1) {
            s += __shfl_xor(s, off);
            sq += __shfl_xor(sq, off);
        }
        float m = s * (1.f / 64.f);
        float var = sq * (1.f / 64.f) - m * m;
        float xh = (acc - m) * rsqrtf(var + EPS) * g[j] + bb[j];
        float r = fmaxf(xh, 0.f);
        float l[3];
#pragma unroll
        for (int c = 0; c < 3; ++c) {
            float p = r * W2[c * 64 + j];
#pragma unroll
            for (int off = 32; off; off >>= 1) p += __shfl_xor(p, off);
            l[c] = p + b2[c];
        }
        if (j == 0) {
            float mx = fmaxf(l[0], fmaxf(l[1], l[2]));
            float e0 = expf(l[0] - mx), e1 = expf(l[1] - mx), e2 = expf(l[2] - mx);
            float inv = 1.f / (e0 + e1 + e2);
            wmix[h * 3 + 0] = e0 * inv;
            wmix[h * 3 + 1] = e1 * inv;
            wmix[h * 3 + 2] = e2 * inv;
        }
        return;
    }
    int hb = blockIdx.x, kz = blockIdx.y;
    int h = hb >> 2, b = hb & 3;
    // raw row-major staging (stride 72 shorts) + K-major tiles (stride 40)
    __shared__ __attribute__((aligned(16))) short rawK[32 * 72];
    __shared__ __attribute__((aligned(16))) short rawV[32 * 72];
    __shared__ __attribute__((aligned(16))) short Ktp[64 * 40];
    __shared__ __attribute__((aligned(16))) short Ktr[64 * 40];
    __shared__ __attribute__((aligned(16))) short Vt[64 * 40];
    __shared__ float rs[256], kvs[256], mks[256];
    {
        int sidx = h * ROWS + b * 1024 + kz * 256 + t;
        rs[t] = rnk[sidx];
        kvs[t] = kvv[sidx];
        mks[t] = mkm[sidx];
    }
    int w = t >> 6, lane = t & 63;
    int wm = (w & 1) * 32, wn = (w >> 1) * 32;
    floatx4 accP[2][2], accR[2][2];
#pragma unroll
    for (int i = 0; i < 2; ++i)
#pragma unroll
        for (int j = 0; j < 2; ++j) {
            accP[i][j] = (floatx4){0.f, 0.f, 0.f, 0.f};
            accR[i][j] = (floatx4){0.f, 0.f, 0.f, 0.f};
        }
    float skv_acc = 0.f, smk_acc = 0.f;
    int mrow = t >> 3, dcol = (t & 7) * 8;  // stage-1 thread map
    int dT = t >> 2, mg = (t & 3) * 8;      // stage-2 (transpose) map
    int krow = (lane >> 4) * 8;

    for (int s = 0; s < 8; ++s) {
        size_t gbase =
            (size_t)(b * 1024 + kz * 256 + s * 32 + mrow) * 512 + h * 64 + dcol;
        short8 k8 = *(const short8*)&fkb[gbase];
        short8 v8 = *(const short8*)&fvb[gbase];
        *(short8*)&rawK[mrow * 72 + dcol] = k8;
        *(short8*)&rawV[mrow * 72 + dcol] = v8;
        __syncthreads();
        // transpose + scale + skv/smk partials
        short8 okp, okr, ov;
        int mb = s * 32 + mg;
#pragma unroll
        for (int i = 0; i < 8; ++i) {
            short kv_ = rawK[(mg + i) * 72 + dT];
            float kf = bf2f(kv_);
            okp[i] = kv_;
            okr[i] = f2bf(kf * rs[mb + i]);
            short vv_ = rawV[(mg + i) * 72 + dT];
            ov[i] = vv_;
            float vf = bf2f(vv_);
            skv_acc += kvs[mb + i] * vf;
            smk_acc += mks[mb + i] * vf;
        }
        *(short8*)&Ktp[dT * 40 + mg] = okp;
        *(short8*)&Ktr[dT * 40 + mg] = okr;
        *(short8*)&Vt[dT * 40 + mg] = ov;
        __syncthreads();
        short8 afp[2], afr[2], bfv[2];
#pragma unroll
        for (int i = 0; i < 2; ++i) {
            afp[i] = *(const short8*)&Ktp[(wm + i * 16 + (lane & 15)) * 40 + krow];
            afr[i] = *(const short8*)&Ktr[(wm + i * 16 + (lane & 15)) * 40 + krow];
            bfv[i] = *(const short8*)&Vt[(wn + i * 16 + (lane & 15)) * 40 + krow];
        }
#pragma unroll
        for (int i = 0; i < 2; ++i)
#pragma unroll
            for (int j = 0; j < 2; ++j) {
                accP[i][j] = __builtin_amdgcn_mfma_f32_16x16x32_bf16(
                    afp[i], bfv[j], accP[i][j], 0, 0, 0);
                accR[i][j] = __builtin_amdgcn_mfma_f32_16x16x32_bf16(
                    afr[i], bfv[j], accR[i][j], 0, 0, 0);
            }
        __syncthreads();
    }
    int col = lane & 15, rbase = (lane >> 4) * 4;
    float* Cb = Mnew + (size_t)hb * 8192;
#pragma unroll
    for (int i = 0; i < 2; ++i)
#pragma unroll
        for (int j = 0; j < 2; ++j)
#pragma unroll
            for (int r = 0; r < 4; ++r) {
                int ci = (wm + i * 16 + rbase + r) * 64 + wn + j * 16 + col;
                atomicAdd(&Cb[ci], accP[i][j][r]);
                atomicAdd(&Cb[4096 + ci], accR[i][j][r]);
            }
    atomicAdd(&Sv[hb * 128 + dT], skv_acc);
    atomicAdd(&Sv[hb * 128 + 64 + dT], smk_acc);
}

// ---------------------------------------------------------------------------
// Q-side apply, 64 rows per block. grid (16, 32). fq input bf16.
// Mnew layout: [hb][0:4096]=M2, [4096:8192]=M1.  Sv: [hb][0:64]=skv,[64:128]=smk.
// ---------------------------------------------------------------------------
__global__ __launch_bounds__(256) void qside(
    const short* __restrict__ fqb, const float* __restrict__ Mnew,
    const float* __restrict__ Sv, const float* __restrict__ rnq,
    const float* __restrict__ mq, const float* __restrict__ qv,
    const float* __restrict__ wmix, short* __restrict__ attn_out) {
    int ntile = blockIdx.x, hb = blockIdx.y;
    int h = hb >> 2, b = hb & 3;
    __shared__ float M1s[4096], M2s[4096], fqt[4096];
    __shared__ float Skvs[64], Smks[64], rnqs[64], mqs[64], qvs[64];
    int t = threadIdx.x;
    const float* base = Mnew + (size_t)hb * 8192;
#pragma unroll
    for (int u = 0; u < 4; ++u) {
        int idx = t * 4 + u * 1024;
        *(float4*)&M2s[idx] = *(const float4*)&base[idx];
        *(float4*)&M1s[idx] = *(const float4*)&base[4096 + idx];
    }
    int n0 = ntile * 64;
#pragma unroll
    for (int u = 0; u < 2; ++u) {
        int idx = t * 8 + u * 2048;
        int r = idx >> 6, d = idx & 63;
        short8 sv = *(const short8*)&fqb[(size_t)(b * 1024 + n0 + r) * 512 + h * 64 + d];
#pragma unroll
        for (int i = 0; i < 8; ++i) fqt[idx + i] = bf2f(sv[i]);
    }
    if (t < 64) {
        Skvs[t] = Sv[hb * 128 + t];
        Smks[t] = Sv[hb * 128 + 64 + t];
        int sidx = h * ROWS + b * 1024 + n0 + t;
        rnqs[t] = rnq[sidx];
        mqs[t] = mq[sidx];
        qvs[t] = qv[sidx];
    }
    __syncthreads();
    float cw = wmix[h * 3 + 0], covw = wmix[h * 3 + 1], vw = wmix[h * 3 + 2];
    int e = t & 63, rq = t >> 6;
    float a1[16] = {}, a2[16] = {};
    for (int d4 = 0; d4 < 64; d4 += 4) {
        float md1[4], md2[4];
#pragma unroll
        for (int dd = 0; dd < 4; ++dd) {
            md1[dd] = M1s[(d4 + dd) * 64 + e];
            md2[dd] = M2s[(d4 + dd) * 64 + e];
        }
#pragma unroll
        for (int i = 0; i < 16; ++i) {
            float4 f = *(const float4*)&fqt[(rq * 16 + i) * 64 + d4];
            a1[i] += f.x * md1[0] + f.y * md1[1] + f.z * md1[2] + f.w * md1[3];
            a2[i] += f.x * md2[0] + f.y * md2[1] + f.z * md2[2] + f.w * md2[3];
        }
    }
    float c2 = covw * (1.f / 64.f), c3 = vw * (1.f / 64.f);
#pragma unroll
    for (int i = 0; i < 16; ++i) {
        int rr = rq * 16 + i;
        float v = cw * rnqs[rr] * a1[i] + c2 * a2[i] + c3 * qvs[rr] * Skvs[e] -
                  covw * mqs[rr] * Smks[e];
        attn_out[(size_t)(b * 1024 + n0 + rr) * 512 + h * 64 + e] = f2bf(v);
    }
}

// ---------------------------------------------------------------------------
extern "C" void kernel_launch(void* const* d_in, const int* in_sizes, int n_in,
                              void* d_out, int out_size, void* d_ws, size_t ws_size,
                              hipStream_t stream) {
    const float* q = (const float*)d_in[0];
    const float* k = (const float*)d_in[1];
    const float* v = (const float*)d_in[2];
    const float* Win = (const float*)d_in[3];
    const float* Wout = (const float*)d_in[4];
    const float* bout = (const float*)d_in[5];
    const float* g1 = (const float*)d_in[6];
    const float* b1n = (const float*)d_in[7];
    const float* g2 = (const float*)d_in[8];
    const float* b2n = (const float*)d_in[9];
    const float* Wup = (const float*)d_in[10];
    const float* bup = (const float*)d_in[11];
    const float* Wdn = (const float*)d_in[12];
    const float* bdn = (const float*)d_in[13];
    const float* wpW1 = (const float*)d_in[14];
    const float* wpb1 = (const float*)d_in[15];
    const float* wpg = (const float*)d_in[16];
    const float* wpb = (const float*)d_in[17];
    const float* wpW2 = (const float*)d_in[18];
    const float* wpb2 = (const float*)d_in[19];
    float* out = (float*)d_out;

    float* wsf = (float*)d_ws;
    // bf16 fqkv [12288][512]: fq rows 0-4095, fk 4096-8191, fv 8192-12287
    short* fqkv = (short*)wsf;                    // [0, 3145728) floats
    short* fkb = fqkv + (size_t)4096 * 512;
    short* fvb = fqkv + (size_t)8192 * 512;
    short* qkvln = (short*)(wsf + 3145728);       // [3145728, 6291456) floats
    short* hmid = (short*)wsf;                    // [0, 4194304) floats (MLP)
    short* attnbf = (short*)(wsf + 4194304);      // qside output
    short* q2bf = (short*)(wsf + 7340032);        // [7340032, 8388608) floats
    short* Winbf = (short*)(wsf + 8388608);
    short* Woutbf = (short*)(wsf + 8388608 + 131072);
    short* Wupbf = (short*)(wsf + 8388608 + 262144);
    short* Wdnbf = (short*)(wsf + 8388608 + 262144 + 524288);
    float* S = wsf + 9699328;        // [2][3][32768] head stats
    float* qg = S + 196608;          // 512   (zero region start)
    float* kg = qg + 512;            // 512
    float* Mnew = kg + 512;          // 262144
    float* Sv = Mnew + 262144;       // 4096
    float* rowstats = Sv + 4096;     // 8192 (rowsum 4096 + rowsumsq 4096)
    float* wmix = rowstats + 8192;   // 32  (not zeroed)
    float* Bn = wmix + 32;           // 2048 (not zeroed)
    float* Wg = Bn + 2048;           // 2048 (not zeroed)
    float* mqS = S, *rnqS = S + 32768, *qvS = S + 65536;
    float* mkS = S + 98304, *rnkS = S + 131072, *kvS = S + 163840;

    // 1. fused prep: LN(q/k/v)->bf16, weights->bf16 (+Bn/Wg), zero stats
    prep<<<4621, 256, 0, stream>>>(q, k, v, g1, b1n, qkvln,
                                   Win, Wout, Wup, Wdn,
                                   Winbf, Woutbf, Wupbf, Wdnbf,
                                   g2, b2n, Bn, Wg, qg);

    // 2. stacked projection -> bf16 fqkv + fused head-stats/colmeans
    mfma_gemm_nt<64, 128, 1, true><<<dim3(4, 192), 256, 0, stream>>>(
        qkvln, Winbf, fqkv, 12288, 512, 512, 512, nullptr, nullptr, nullptr,
        S, qg, kg);

    // 3. fused kside: in-LDS transpose + MFMA -> Mnew, skv/smk, policy MLP
    kside_fused<<<dim3(33, 4), 256, 0, stream>>>(
        fkb, fvb, rnkS, kvS, mkS, Mnew, Sv,
        qg, kg, wpW1, wpb1, wpg, wpb, wpW2, wpb2, wmix);

    // 4. Q-side apply
    qside<<<dim3(16, 32), 256, 0, stream>>>(fqkv, Mnew, Sv, rnqS, mqS, qvS,
                                            wmix, attnbf);

    // 5. q2 = q + attn @ Wout^T + bout -> out(f32) + q2bf(bf16) + rowstats
    mfma_gemm_nt<64, 64, 5, false><<<dim3(8, 64), 256, 0, stream>>>(
        attnbf, Woutbf, out, 4096, 512, 512, 512, bout, q, q2bf,
        rowstats, nullptr, nullptr);

    // 6. MLP-up with LN folded: h = gelu(rstd*(q2@Wup'^T) + Bn + bup - m*rstd*Wg)
    mfma_gemm_nt<64, 128, 4, true><<<dim3(16, 64), 256, 0, stream>>>(
        q2bf, Wupbf, hmid, 4096, 2048, 512, 512, bup, nullptr, nullptr,
        rowstats, Bn, Wg);

    // 7. out = q2 + h@Wdn^T + bdn
    mfma_gemm_nt<64, 128, 2, false><<<dim3(4, 64), 256, 0, stream>>>(
        hmid, Wdnbf, out, 4096, 512, 2048, 2048, bdn, out, nullptr,
        nullptr, nullptr, nullptr);
}